// Round 1
// baseline (312.096 us; speedup 1.0000x reference)
//
#include <hip/hip_runtime.h>

#define NN 4
#define CC 64
#define GG 4
#define GCC 16
#define HH 128
#define WW 128
#define LL (HH*WW)
#define OMS 112   /* padded om row stride (floats); per-group stride 28 */

// ---------------------------------------------------------------------------
// Kernel 1: per-pixel GEMV producing v[n][l][64] and om[n][l][112] (pixel-major)
//   grid = N * 64 tiles * 2 halves; block = 256 threads (1 pixel/thread)
//   half 0 computes chunks 0..5  (v cols 0..63 + om rows 0..31)
//   half 1 computes chunks 6..10 (om rows 32..111)
//   om storage remap: row r (0..107) -> col r + r/27  (group g at col g*28,
//   27 used + 1 pad) so kernel 2 reads 7 aligned float4 per group.
// ---------------------------------------------------------------------------
__global__ __launch_bounds__(256) void vm_kernel(
    const float* __restrict__ x,
    const float* __restrict__ value_w, const float* __restrict__ value_b,
    const float* __restrict__ om_w,    const float* __restrict__ om_b,
    float* __restrict__ vws, float* __restrict__ omws)
{
  __shared__ float lds_t[16][257];   // +1 pad breaks bank aliasing on staged reads
  const int t    = threadIdx.x;
  const int bid  = blockIdx.x;
  const int half = bid & 1;
  const int tile = (bid >> 1) & 63;
  const int n    = bid >> 7;
  const int l0   = tile << 8;
  const int l    = l0 + t;

  // x row (64 channels) into registers; coalesced per-channel loads
  float xr[64];
  const float* xp = x + ((size_t)n * CC) * LL + l;
  #pragma unroll
  for (int k = 0; k < 64; ++k) xr[k] = xp[(size_t)k * LL];

  const int c_beg = half ? 6 : 0;
  const int c_end = half ? 11 : 6;
  for (int ch = c_beg; ch < c_end; ++ch) {
    const bool is_v = (ch < 4);
    const int  oc   = is_v ? (ch << 4) : ((ch - 4) << 4);
    const float* __restrict__ wgt = is_v ? value_w : om_w;
    const float* __restrict__ bia = is_v ? value_b : om_b;

    float acc[16];
    #pragma unroll
    for (int j = 0; j < 16; ++j) acc[j] = bia[oc + j];

    // fully unrolled so xr[] / acc[] stay in registers (no scratch)
    #pragma unroll
    for (int k = 0; k < 64; ++k) {
      const float xv = xr[k];
      #pragma unroll
      for (int j = 0; j < 16; ++j)
        acc[j] = fmaf(xv, wgt[(size_t)(oc + j) * 64 + k], acc[j]);
    }

    // destination column for the cooperative (transposed) store
    const int q = oc + (t & 15);
    int col, valid; size_t rowstride; float* dbase;
    if (is_v) {
      col = q; valid = 1; rowstride = 64;
      dbase = vws + ((size_t)n * LL + l0) * 64;
    } else {
      const int d = (q >= 81) ? 3 : (q >= 54) ? 2 : (q >= 27) ? 1 : 0;
      col = q + d; valid = (q < 108); rowstride = OMS;
      dbase = omws + ((size_t)n * LL + l0) * OMS;
    }

    __syncthreads();                       // protect lds_t reuse across chunks
    #pragma unroll
    for (int j = 0; j < 16; ++j) lds_t[j][t] = acc[j];   // 2 lanes/bank: free
    __syncthreads();
    if (valid) {
      const int j2 = t & 15, r0 = t >> 4;
      #pragma unroll
      for (int pass = 0; pass < 16; ++pass) {
        const int r = r0 + (pass << 4);
        // 16-lane contiguous 64B runs (v rows 256B, om rows 448B, both 64B-aligned)
        dbase[(size_t)r * rowstride + col] = lds_t[j2][r];
      }
    }
  }
}

// ---------------------------------------------------------------------------
// Kernel 2: deformable bilinear gather + output GEMV, NCHW store
//   grid = N * 64 tiles; block = 256 threads (1 pixel/thread)
// ---------------------------------------------------------------------------
__global__ __launch_bounds__(256) void dcn_kernel(
    const float* __restrict__ vws, const float* __restrict__ omws,
    const float* __restrict__ out_w, const float* __restrict__ out_b,
    float* __restrict__ out)
{
  const int t   = threadIdx.x;
  const int bid = blockIdx.x;
  const int n   = bid >> 6;
  const int l   = ((bid & 63) << 8) + t;
  const float pyf = (float)(l >> 7);
  const float pxf = (float)(l & (WW - 1));
  const float* __restrict__ omp_  = omws + ((size_t)n * LL + l) * OMS;
  const float* __restrict__ vbase = vws + (size_t)n * LL * CC;

  float s[64];
  #pragma unroll
  for (int i = 0; i < 64; ++i) s[i] = 0.0f;

  #pragma unroll
  for (int g = 0; g < GG; ++g) {
    // 28 floats per group (27 used + pad), 7 aligned float4 loads
    float buf[28];
    const float4* og4 = (const float4*)(omp_ + g * 28);
    #pragma unroll
    for (int i = 0; i < 7; ++i) {
      const float4 vv = og4[i];
      buf[4*i+0] = vv.x; buf[4*i+1] = vv.y; buf[4*i+2] = vv.z; buf[4*i+3] = vv.w;
    }
    #pragma unroll
    for (int p = 0; p < 9; ++p) {
      const float sy  = pyf + (float)(p / 3 - 1) + buf[2*p+1];  // off[...,1] = y
      const float sx  = pxf + (float)(p % 3 - 1) + buf[2*p+0];  // off[...,0] = x
      const float y0f = floorf(sy), x0f = floorf(sx);
      const float wy  = sy - y0f,  wx  = sx - x0f;
      const int   iy  = (int)y0f,  ix  = (int)x0f;
      const float m   = buf[18 + p];
      const float w00 = (1.0f - wy) * (1.0f - wx) * m;
      const float w01 = (1.0f - wy) * wx * m;
      const float w10 = wy * (1.0f - wx) * m;
      const float w11 = wy * wx * m;
      #pragma unroll
      for (int cor = 0; cor < 4; ++cor) {
        const int   cy = iy + (cor >> 1);
        const int   cx = ix + (cor & 1);
        const float w  = (cor == 0) ? w00 : (cor == 1) ? w01 : (cor == 2) ? w10 : w11;
        if (cy >= 0 && cy < HH && cx >= 0 && cx < WW) {
          const float4* vp4 =
              (const float4*)(vbase + ((size_t)(cy * WW + cx) * CC) + g * GCC);
          #pragma unroll
          for (int qq = 0; qq < 4; ++qq) {
            const float4 vv = vp4[qq];
            s[g*16 + 4*qq + 0] = fmaf(w, vv.x, s[g*16 + 4*qq + 0]);
            s[g*16 + 4*qq + 1] = fmaf(w, vv.y, s[g*16 + 4*qq + 1]);
            s[g*16 + 4*qq + 2] = fmaf(w, vv.z, s[g*16 + 4*qq + 2]);
            s[g*16 + 4*qq + 3] = fmaf(w, vv.w, s[g*16 + 4*qq + 3]);
          }
        }
      }
    }
  }

  // y = s @ out_w^T + out_b; NCHW store (lane = consecutive pixel: coalesced)
  float* op = out + ((size_t)n * CC) * LL + l;
  for (int c = 0; c < 64; ++c) {          // rolled: code stays small
    float y = out_b[c];
    #pragma unroll
    for (int k = 0; k < 64; ++k)          // full unroll: s[] static-indexed
      y = fmaf(s[k], out_w[(size_t)c * 64 + k], y);
    op[(size_t)c * LL] = y;
  }
}

// ---------------------------------------------------------------------------
extern "C" void kernel_launch(void* const* d_in, const int* in_sizes, int n_in,
                              void* d_out, int out_size, void* d_ws, size_t ws_size,
                              hipStream_t stream) {
  const float* x       = (const float*)d_in[0];
  const float* value_w = (const float*)d_in[1];
  const float* value_b = (const float*)d_in[2];
  const float* om_w    = (const float*)d_in[3];
  const float* om_b    = (const float*)d_in[4];
  const float* out_w   = (const float*)d_in[5];
  const float* out_b   = (const float*)d_in[6];
  float* outp = (float*)d_out;

  float* vws  = (float*)d_ws;                       // 4*16384*64  f32 = 16 MB
  float* omws = vws + (size_t)NN * LL * CC;         // 4*16384*112 f32 = 28 MB

  vm_kernel<<<dim3(NN * 64 * 2), dim3(256), 0, stream>>>(
      x, value_w, value_b, om_w, om_b, vws, omws);
  dcn_kernel<<<dim3(NN * 64), dim3(256), 0, stream>>>(
      vws, omws, out_w, out_b, outp);
}

// Round 2
// 247.817 us; speedup vs baseline: 1.2594x; 1.2594x over previous
//
#include <hip/hip_runtime.h>

#define NN 4
#define CC 64
#define GG 4
#define GCC 16
#define HH 128
#define WW 128
#define LL (HH*WW)
#define OMS 112   /* padded om row stride (floats); per-group stride 28 */

// ---------------------------------------------------------------------------
// Kernel 1: per-pixel GEMV producing v[n][l][64] and om[n][l][112] (pixel-major)
//   grid = (N*64 tiles, 11 chunks); block = 256 threads (1 pixel/thread)
//   Each block computes ONE 16-wide output chunk for 256 pixels:
//     chunks 0..3  -> v cols 0..63
//     chunks 4..10 -> om rows 0..111 (remapped: row r -> col r + r/27, so
//                     group g starts at col g*28; kernel 2 reads 7 float4)
//   11264 waves total (~5/SIMD) so weight s_load latency is hidden.
// ---------------------------------------------------------------------------
__global__ __launch_bounds__(256) void vm_kernel(
    const float* __restrict__ x,
    const float* __restrict__ value_w, const float* __restrict__ value_b,
    const float* __restrict__ om_w,    const float* __restrict__ om_b,
    float* __restrict__ vws, float* __restrict__ omws)
{
  __shared__ float lds_t[16][257];   // +1 pad: staged reads 2-way max (free)
  const int t    = threadIdx.x;
  const int ch   = blockIdx.y;       // 0..10
  const int bid  = blockIdx.x;       // n*64 + tile
  const int tile = bid & 63;
  const int n    = bid >> 6;
  const int l0   = tile << 8;
  const int l    = l0 + t;

  // x row (64 channels) into registers; per-channel loads are wave-coalesced
  float xr[64];
  const float* xp = x + ((size_t)n * CC) * LL + l;
  #pragma unroll
  for (int k = 0; k < 64; ++k) xr[k] = xp[(size_t)k * LL];

  const bool is_v = (ch < 4);
  const int  oc   = is_v ? (ch << 4) : ((ch - 4) << 4);
  const float* __restrict__ wgt = is_v ? value_w : om_w;
  const float* __restrict__ bia = is_v ? value_b : om_b;

  float acc[16];
  #pragma unroll
  for (int j = 0; j < 16; ++j) acc[j] = bia[oc + j];

  // fully unrolled: xr[]/acc[] static-indexed, weights wave-uniform (s_load)
  #pragma unroll
  for (int k = 0; k < 64; ++k) {
    const float xv = xr[k];
    #pragma unroll
    for (int j = 0; j < 16; ++j)
      acc[j] = fmaf(xv, wgt[(size_t)(oc + j) * 64 + k], acc[j]);
  }

  // destination column (om rows remapped with per-group pad)
  const int q = oc + (t & 15);
  int col, valid; size_t rowstride; float* dbase;
  if (is_v) {
    col = q; valid = 1; rowstride = 64;
    dbase = vws + ((size_t)n * LL + l0) * 64;
  } else {
    const int d = (q >= 81) ? 3 : (q >= 54) ? 2 : (q >= 27) ? 1 : 0;
    col = q + d; valid = (q < 108); rowstride = OMS;
    dbase = omws + ((size_t)n * LL + l0) * OMS;
  }

  #pragma unroll
  for (int j = 0; j < 16; ++j) lds_t[j][t] = acc[j];   // 2 lanes/bank: free
  __syncthreads();
  if (valid) {
    const int j2 = t & 15, r0 = t >> 4;
    #pragma unroll
    for (int pass = 0; pass < 16; ++pass) {
      const int r = r0 + (pass << 4);
      // 16-lane contiguous 64B runs (v rows 256B, om rows 448B, 64B-aligned)
      dbase[(size_t)r * rowstride + col] = lds_t[j2][r];
    }
  }
}

// ---------------------------------------------------------------------------
// Kernel 2: deformable bilinear gather + output GEMV, NCHW store
//   grid = N*256 blocks; block = 256 threads over 64 pixels, two phases:
//     phase A (gather): thread = (pixel, group); s_g[16] -> LDS
//     phase B (GEMV)  : thread = (pixel, c-quarter); cq is wave-uniform so
//                       out_w reads stay on the scalar path; store coalesced
// ---------------------------------------------------------------------------
__global__ __launch_bounds__(256) void dcn_kernel(
    const float* __restrict__ vws, const float* __restrict__ omws,
    const float* __restrict__ out_w, const float* __restrict__ out_b,
    float* __restrict__ out)
{
  __shared__ float s_lds[64][65];    // stride 65: bank=(p+k)%32, 2-way max
  const int t   = threadIdx.x;
  const int bid = blockIdx.x;
  const int n   = bid >> 8;
  const int p0  = (bid & 255) << 6;  // 64 pixels per block

  // ---- phase A: gather ----
  {
    const int p = t >> 2;            // 0..63 pixel-in-block
    const int g = t & 3;             // group
    const int l = p0 + p;
    const float pyf = (float)(l >> 7);
    const float pxf = (float)(l & (WW - 1));
    const float* __restrict__ omp_  = omws + ((size_t)n * LL + l) * OMS + g * 28;
    const float* __restrict__ vbase = vws + (size_t)n * LL * CC + g * GCC;

    float buf[28];
    const float4* og4 = (const float4*)omp_;
    #pragma unroll
    for (int i = 0; i < 7; ++i) {
      const float4 vv = og4[i];
      buf[4*i+0] = vv.x; buf[4*i+1] = vv.y; buf[4*i+2] = vv.z; buf[4*i+3] = vv.w;
    }

    float s[16];
    #pragma unroll
    for (int i = 0; i < 16; ++i) s[i] = 0.0f;

    #pragma unroll
    for (int pp = 0; pp < 9; ++pp) {
      const float sy  = pyf + (float)(pp / 3 - 1) + buf[2*pp+1];
      const float sx  = pxf + (float)(pp % 3 - 1) + buf[2*pp+0];
      const float y0f = floorf(sy), x0f = floorf(sx);
      const float wy  = sy - y0f,  wx  = sx - x0f;
      const int   iy  = (int)y0f,  ix  = (int)x0f;
      const float m   = buf[18 + pp];
      const float w00 = (1.0f - wy) * (1.0f - wx) * m;
      const float w01 = (1.0f - wy) * wx * m;
      const float w10 = wy * (1.0f - wx) * m;
      const float w11 = wy * wx * m;
      #pragma unroll
      for (int cor = 0; cor < 4; ++cor) {
        const int   cy = iy + (cor >> 1);
        const int   cx = ix + (cor & 1);
        const float w  = (cor == 0) ? w00 : (cor == 1) ? w01 : (cor == 2) ? w10 : w11;
        if (cy >= 0 && cy < HH && cx >= 0 && cx < WW) {
          const float4* vp4 = (const float4*)(vbase + (size_t)(cy * WW + cx) * CC);
          #pragma unroll
          for (int qq = 0; qq < 4; ++qq) {
            const float4 vv = vp4[qq];
            s[4*qq+0] = fmaf(w, vv.x, s[4*qq+0]);
            s[4*qq+1] = fmaf(w, vv.y, s[4*qq+1]);
            s[4*qq+2] = fmaf(w, vv.z, s[4*qq+2]);
            s[4*qq+3] = fmaf(w, vv.w, s[4*qq+3]);
          }
        }
      }
    }
    #pragma unroll
    for (int j = 0; j < 16; ++j) s_lds[p][g * 16 + j] = s[j];
  }
  __syncthreads();

  // ---- phase B: output GEMV + NCHW store ----
  {
    const int p  = t & 63;           // pixel-in-block (lane id)
    const int cq = t >> 6;           // c-quarter, uniform per wave
    const int l  = p0 + p;
    float y[16];
    #pragma unroll
    for (int j = 0; j < 16; ++j) y[j] = out_b[cq * 16 + j];
    #pragma unroll 4
    for (int k = 0; k < 64; ++k) {
      const float sv = s_lds[p][k];                  // 2-way bank alias: free
      #pragma unroll
      for (int j = 0; j < 16; ++j)                   // weights wave-uniform
        y[j] = fmaf(sv, out_w[(size_t)(cq * 16 + j) * 64 + k], y[j]);
    }
    float* op = out + ((size_t)n * CC) * LL + l;
    #pragma unroll
    for (int j = 0; j < 16; ++j)
      op[(size_t)(cq * 16 + j) * LL] = y[j];         // 256B coalesced runs
  }
}

// ---------------------------------------------------------------------------
extern "C" void kernel_launch(void* const* d_in, const int* in_sizes, int n_in,
                              void* d_out, int out_size, void* d_ws, size_t ws_size,
                              hipStream_t stream) {
  const float* x       = (const float*)d_in[0];
  const float* value_w = (const float*)d_in[1];
  const float* value_b = (const float*)d_in[2];
  const float* om_w    = (const float*)d_in[3];
  const float* om_b    = (const float*)d_in[4];
  const float* out_w   = (const float*)d_in[5];
  const float* out_b   = (const float*)d_in[6];
  float* outp = (float*)d_out;

  float* vws  = (float*)d_ws;                       // 4*16384*64  f32 = 16 MB
  float* omws = vws + (size_t)NN * LL * CC;         // 4*16384*112 f32 = 28 MB

  vm_kernel<<<dim3(NN * 64, 11), dim3(256), 0, stream>>>(
      x, value_w, value_b, om_w, om_b, vws, omws);
  dcn_kernel<<<dim3(NN * 256), dim3(256), 0, stream>>>(
      vws, omws, out_w, out_b, outp);
}

// Round 3
// 162.964 us; speedup vs baseline: 1.9151x; 1.5207x over previous
//
#include <hip/hip_runtime.h>

#define NN 4
#define CC 64
#define GG 4
#define GCC 16
#define HH 128
#define WW 128
#define LL (HH*WW)
#define OMS 112        /* om row stride (floats); group g at col 28g, 27 used + pad */
#define WPC 192        /* wpack row width: 64 v-cols | 112 om-cols (remapped) | 16 pad */

// ---------------------------------------------------------------------------
// Kernel 0: pack weights.
//   wpack[k][c]: c<64      -> value_w[c][k]
//                64..175   -> om storage col s=c-64; s%28==27 is pad (0),
//                             else om_w[r][k] with r = s - s/28
//                176..191  -> 0
//   bpack[c]   : same column map over value_b / om_b
//   owt[k][c]  : out_w[c][k]
// ---------------------------------------------------------------------------
__global__ void pack_kernel(const float* __restrict__ value_w, const float* __restrict__ value_b,
                            const float* __restrict__ om_w,    const float* __restrict__ om_b,
                            const float* __restrict__ out_w,
                            float* __restrict__ wpack, float* __restrict__ bpack,
                            float* __restrict__ owt)
{
  const int i = blockIdx.x * 256 + threadIdx.x;
  if (i < 64 * WPC) {
    const int k = i / WPC, c = i % WPC;
    float v = 0.0f;
    if (c < 64) v = value_w[c * 64 + k];
    else if (c < 176) {
      const int s = c - 64;
      if (s % 28 != 27) { const int r = s - s / 28; v = om_w[r * 64 + k]; }
    }
    wpack[i] = v;
  }
  if (i < WPC) {
    float v = 0.0f;
    if (i < 64) v = value_b[i];
    else if (i < 176) {
      const int s = i - 64;
      if (s % 28 != 27) { const int r = s - s / 28; v = om_b[r]; }
    }
    bpack[i] = v;
  }
  if (i < 64 * 64) {
    const int k = i >> 6, c = i & 63;
    owt[i] = out_w[c * 64 + k];
  }
}

// ---------------------------------------------------------------------------
// Kernel 1: x @ [value_w|om_w].T -> vws (pixel-major, 64) + omws (112, padded)
//   grid = (128 pixel-tiles of 512, 11 chunks); block 256, 2 px/thread.
//   Chunk weights live in LDS; all lanes read the same address -> broadcast
//   (no bank conflict, no SGPR pressure). Remap baked into wpack makes every
//   chunk's 16 output cols contiguous -> pure float4 stores.
// ---------------------------------------------------------------------------
__global__ __launch_bounds__(256) void vm_kernel(
    const float* __restrict__ x, const float* __restrict__ wpack,
    const float* __restrict__ bpack,
    float* __restrict__ vws, float* __restrict__ omws)
{
  __shared__ float wlds[64][16];     // 4KB; uniform reads -> broadcast
  const int t    = threadIdx.x;
  const int ch   = blockIdx.y;       // 0..10
  const int col0 = ch << 4;

  {
    const int k = t >> 2, q = t & 3;
    *(float4*)&wlds[k][q * 4] =
        *(const float4*)&wpack[k * WPC + col0 + q * 4];
  }
  float b[16];
  #pragma unroll
  for (int j = 0; j < 16; ++j) b[j] = bpack[col0 + j];
  __syncthreads();

  const int l0  = blockIdx.x << 9;         // 512 px per block; never straddles n
  const int n   = l0 >> 14;
  const int hw  = (l0 & (LL - 1)) + t;     // pixel for pi=0; pi=1 is +256

  float acc0[16], acc1[16];
  #pragma unroll
  for (int j = 0; j < 16; ++j) { acc0[j] = b[j]; acc1[j] = b[j]; }

  const float* xb = x + (size_t)n * CC * LL + hw;
  #pragma unroll 8
  for (int k = 0; k < 64; ++k) {
    const float xv0 = xb[(size_t)k * LL];
    const float xv1 = xb[(size_t)k * LL + 256];
    #pragma unroll
    for (int q = 0; q < 4; ++q) {
      const float4 w = *(const float4*)&wlds[k][q * 4];
      acc0[q*4+0] = fmaf(xv0, w.x, acc0[q*4+0]);
      acc0[q*4+1] = fmaf(xv0, w.y, acc0[q*4+1]);
      acc0[q*4+2] = fmaf(xv0, w.z, acc0[q*4+2]);
      acc0[q*4+3] = fmaf(xv0, w.w, acc0[q*4+3]);
      acc1[q*4+0] = fmaf(xv1, w.x, acc1[q*4+0]);
      acc1[q*4+1] = fmaf(xv1, w.y, acc1[q*4+1]);
      acc1[q*4+2] = fmaf(xv1, w.z, acc1[q*4+2]);
      acc1[q*4+3] = fmaf(xv1, w.w, acc1[q*4+3]);
    }
  }

  float* dst; int col; size_t stride;
  if (ch < 4) { dst = vws  + (size_t)n * LL * 64;  col = col0;      stride = 64;  }
  else        { dst = omws + (size_t)n * LL * OMS; col = col0 - 64; stride = OMS; }
  float* d0 = dst + (size_t)hw * stride + col;
  float* d1 = dst + (size_t)(hw + 256) * stride + col;
  #pragma unroll
  for (int q = 0; q < 4; ++q) {
    *(float4*)&d0[q * 4] = make_float4(acc0[q*4+0], acc0[q*4+1], acc0[q*4+2], acc0[q*4+3]);
    *(float4*)&d1[q * 4] = make_float4(acc1[q*4+0], acc1[q*4+1], acc1[q*4+2], acc1[q*4+3]);
  }
}

// ---------------------------------------------------------------------------
// Kernel 2: deformable bilinear gather + output GEMV, NCHW store
//   phase A: thread = (pixel, group) gather -> s_lds
//   phase B: thread = (pixel-lane, c-quarter); out_wT from LDS broadcast
// ---------------------------------------------------------------------------
__global__ __launch_bounds__(256) void dcn_kernel(
    const float* __restrict__ vws, const float* __restrict__ omws,
    const float* __restrict__ owt, const float* __restrict__ out_b,
    float* __restrict__ out)
{
  __shared__ float s_lds[64][65];    // (p + k) % 32 banks: 2-way max (free)
  __shared__ float owlds[64][16*4];  // owt staged; uniform reads -> broadcast
  const int t   = threadIdx.x;
  const int bid = blockIdx.x;
  const int n   = bid >> 8;
  const int p0  = (bid & 255) << 6;  // 64 pixels per block

  {
    const float4* src = (const float4*)owt;
    float4*       dstl = (float4*)owlds;
    #pragma unroll
    for (int i = 0; i < 4; ++i) dstl[i * 256 + t] = src[i * 256 + t];
  }

  // ---- phase A: gather ----
  {
    const int p = t >> 2;            // 0..63 pixel-in-block
    const int g = t & 3;             // group
    const int l = p0 + p;
    const float pyf = (float)(l >> 7);
    const float pxf = (float)(l & (WW - 1));
    const float* __restrict__ omp_  = omws + ((size_t)n * LL + l) * OMS + g * 28;
    const float* __restrict__ vbase = vws + (size_t)n * LL * CC + g * GCC;

    float buf[28];
    const float4* og4 = (const float4*)omp_;
    #pragma unroll
    for (int i = 0; i < 7; ++i) {
      const float4 vv = og4[i];
      buf[4*i+0] = vv.x; buf[4*i+1] = vv.y; buf[4*i+2] = vv.z; buf[4*i+3] = vv.w;
    }

    float s[16];
    #pragma unroll
    for (int i = 0; i < 16; ++i) s[i] = 0.0f;

    #pragma unroll
    for (int pp = 0; pp < 9; ++pp) {
      const float sy  = pyf + (float)(pp / 3 - 1) + buf[2*pp+1];
      const float sx  = pxf + (float)(pp % 3 - 1) + buf[2*pp+0];
      const float y0f = floorf(sy), x0f = floorf(sx);
      const float wy  = sy - y0f,  wx  = sx - x0f;
      const int   iy  = (int)y0f,  ix  = (int)x0f;
      const float m   = buf[18 + pp];
      const float w00 = (1.0f - wy) * (1.0f - wx) * m;
      const float w01 = (1.0f - wy) * wx * m;
      const float w10 = wy * (1.0f - wx) * m;
      const float w11 = wy * wx * m;
      #pragma unroll
      for (int cor = 0; cor < 4; ++cor) {
        const int   cy = iy + (cor >> 1);
        const int   cx = ix + (cor & 1);
        const float w  = (cor == 0) ? w00 : (cor == 1) ? w01 : (cor == 2) ? w10 : w11;
        if (cy >= 0 && cy < HH && cx >= 0 && cx < WW) {
          const float4* vp4 = (const float4*)(vbase + (size_t)(cy * WW + cx) * CC);
          #pragma unroll
          for (int qq = 0; qq < 4; ++qq) {
            const float4 vv = vp4[qq];
            s[4*qq+0] = fmaf(w, vv.x, s[4*qq+0]);
            s[4*qq+1] = fmaf(w, vv.y, s[4*qq+1]);
            s[4*qq+2] = fmaf(w, vv.z, s[4*qq+2]);
            s[4*qq+3] = fmaf(w, vv.w, s[4*qq+3]);
          }
        }
      }
    }
    #pragma unroll
    for (int j = 0; j < 16; ++j) s_lds[p][g * 16 + j] = s[j];
  }
  __syncthreads();

  // ---- phase B: output GEMV + NCHW store ----
  {
    const int p  = t & 63;           // pixel-in-block (lane id)
    const int cq = t >> 6;           // c-quarter, uniform per wave
    const int l  = p0 + p;
    float y[16];
    #pragma unroll
    for (int j = 0; j < 16; ++j) y[j] = out_b[cq * 16 + j];
    #pragma unroll 8
    for (int k = 0; k < 64; ++k) {
      const float sv = s_lds[p][k];
      #pragma unroll
      for (int q = 0; q < 4; ++q) {
        const float4 w = *(const float4*)&owlds[k][cq * 16 + q * 4];
        y[q*4+0] = fmaf(sv, w.x, y[q*4+0]);
        y[q*4+1] = fmaf(sv, w.y, y[q*4+1]);
        y[q*4+2] = fmaf(sv, w.z, y[q*4+2]);
        y[q*4+3] = fmaf(sv, w.w, y[q*4+3]);
      }
    }
    float* op = out + ((size_t)n * CC) * LL + l;
    #pragma unroll
    for (int j = 0; j < 16; ++j)
      op[(size_t)(cq * 16 + j) * LL] = y[j];         // 256B coalesced runs
  }
}

// ---------------------------------------------------------------------------
extern "C" void kernel_launch(void* const* d_in, const int* in_sizes, int n_in,
                              void* d_out, int out_size, void* d_ws, size_t ws_size,
                              hipStream_t stream) {
  const float* x       = (const float*)d_in[0];
  const float* value_w = (const float*)d_in[1];
  const float* value_b = (const float*)d_in[2];
  const float* om_w    = (const float*)d_in[3];
  const float* om_b    = (const float*)d_in[4];
  const float* out_w   = (const float*)d_in[5];
  const float* out_b   = (const float*)d_in[6];
  float* outp = (float*)d_out;

  float* vws   = (float*)d_ws;                          // 4*16384*64  = 16 MB
  float* omws  = vws   + (size_t)NN * LL * CC;          // 4*16384*112 = 28 MB
  float* wpack = omws  + (size_t)NN * LL * OMS;         // 64*192 floats
  float* bpack = wpack + 64 * WPC;                      // 192 floats
  float* owt   = bpack + WPC;                           // 64*64 floats

  pack_kernel<<<dim3(48), dim3(256), 0, stream>>>(
      value_w, value_b, om_w, om_b, out_w, wpack, bpack, owt);
  vm_kernel<<<dim3(128, 11), dim3(256), 0, stream>>>(
      x, wpack, bpack, vws, omws);
  dcn_kernel<<<dim3(NN * 256), dim3(256), 0, stream>>>(
      vws, omws, owt, out_b, outp);
}

// Round 4
// 160.967 us; speedup vs baseline: 1.9389x; 1.0124x over previous
//
#include <hip/hip_runtime.h>

#define NN 4
#define CC 64
#define GG 4
#define GCC 16
#define HH 128
#define WW 128
#define LL (HH*WW)
#define OMS 112        /* om row stride (floats); group g at col 28g, 27 used + pad */
#define WPC 192        /* wpack row width: 64 v-cols | 112 om-cols (remapped) | 16 pad */

// ---------------------------------------------------------------------------
// Kernel 0: pack weights (wpack: transposed value_w|om_w with group-pad remap;
// bpack: matching bias columns; owt: out_w transposed).
// ---------------------------------------------------------------------------
__global__ void pack_kernel(const float* __restrict__ value_w, const float* __restrict__ value_b,
                            const float* __restrict__ om_w,    const float* __restrict__ om_b,
                            const float* __restrict__ out_w,
                            float* __restrict__ wpack, float* __restrict__ bpack,
                            float* __restrict__ owt)
{
  const int i = blockIdx.x * 256 + threadIdx.x;
  if (i < 64 * WPC) {
    const int k = i / WPC, c = i % WPC;
    float v = 0.0f;
    if (c < 64) v = value_w[c * 64 + k];
    else if (c < 176) {
      const int s = c - 64;
      if (s % 28 != 27) { const int r = s - s / 28; v = om_w[r * 64 + k]; }
    }
    wpack[i] = v;
  }
  if (i < WPC) {
    float v = 0.0f;
    if (i < 64) v = value_b[i];
    else if (i < 176) {
      const int s = i - 64;
      if (s % 28 != 27) { const int r = s - s / 28; v = om_b[r]; }
    }
    bpack[i] = v;
  }
  if (i < 64 * 64) {
    const int k = i >> 6, c = i & 63;
    owt[i] = out_w[c * 64 + k];
  }
}

// ---------------------------------------------------------------------------
// Kernel 1: x @ [value_w|om_w].T -> vws (64, pixel-major) + omws (112, padded)
//   grid = (64 tiles of 1024 px, 11 chunks); block 256, 4 px/thread.
//   Per k: 1 address, 4 offset-folded x loads + 4 broadcast ds_read_b128
//   feeding 64 FMA. Chunks of one tile land on one XCD (linear dispatch:
//   (x + 64y) % 8 == x % 8) so the 256KB x-tile is re-read from L2.
// ---------------------------------------------------------------------------
__global__ __launch_bounds__(256) void vm_kernel(
    const float* __restrict__ x, const float* __restrict__ wpack,
    const float* __restrict__ bpack,
    float* __restrict__ vws, float* __restrict__ omws)
{
  __shared__ float wlds[64][16];     // 4KB; uniform reads -> broadcast
  const int t    = threadIdx.x;
  const int ch   = blockIdx.y;       // 0..10
  const int col0 = ch << 4;

  {
    const int k = t >> 2, q = t & 3;
    *(float4*)&wlds[k][q * 4] =
        *(const float4*)&wpack[k * WPC + col0 + q * 4];
  }
  float b[16];
  #pragma unroll
  for (int j = 0; j < 16; ++j) b[j] = bpack[col0 + j];
  __syncthreads();

  const int l0 = blockIdx.x << 10;         // 1024 px per block (16 tiles / n)
  const int n  = l0 >> 14;
  const int hw = (l0 & (LL - 1)) + t;      // +0, +256, +512, +768

  float acc[4][16];
  #pragma unroll
  for (int pi = 0; pi < 4; ++pi)
    #pragma unroll
    for (int j = 0; j < 16; ++j) acc[pi][j] = b[j];

  const float* xb = x + (size_t)n * CC * LL + hw;
  #pragma unroll 8
  for (int k = 0; k < 64; ++k) {
    float xv[4];
    #pragma unroll
    for (int pi = 0; pi < 4; ++pi) xv[pi] = xb[(size_t)k * LL + pi * 256];
    #pragma unroll
    for (int q = 0; q < 4; ++q) {
      const float4 w = *(const float4*)&wlds[k][q * 4];
      #pragma unroll
      for (int pi = 0; pi < 4; ++pi) {
        acc[pi][q*4+0] = fmaf(xv[pi], w.x, acc[pi][q*4+0]);
        acc[pi][q*4+1] = fmaf(xv[pi], w.y, acc[pi][q*4+1]);
        acc[pi][q*4+2] = fmaf(xv[pi], w.z, acc[pi][q*4+2]);
        acc[pi][q*4+3] = fmaf(xv[pi], w.w, acc[pi][q*4+3]);
      }
    }
  }

  float* dst; int col; int stride;
  if (ch < 4) { dst = vws  + (size_t)n * LL * 64;  col = col0;      stride = 64;  }
  else        { dst = omws + (size_t)n * LL * OMS; col = col0 - 64; stride = OMS; }
  #pragma unroll
  for (int pi = 0; pi < 4; ++pi) {
    float* d = dst + (size_t)(hw + pi * 256) * stride + col;
    #pragma unroll
    for (int q = 0; q < 4; ++q)
      *(float4*)&d[q * 4] =
          make_float4(acc[pi][q*4+0], acc[pi][q*4+1], acc[pi][q*4+2], acc[pi][q*4+3]);
  }
}

// ---------------------------------------------------------------------------
// Kernel 2: deformable bilinear gather + output GEMV, NCHW store.
//   512 threads / block, one image row (128 px). XCD-aware: n = (B&7)>>1,
//   row-band = ((B&7)&1)*64 + B/8 -> each XCD L2 holds exactly one image's v
//   (4 MB) in contiguous row order. 3 blocks/CU -> 24 waves/CU.
//   phase A: thread = (pixel, group) gather -> s_lds
//   phase B: thread = (pixel-lane, c-quarter); weights broadcast from LDS
// ---------------------------------------------------------------------------
__global__ __launch_bounds__(512) void dcn_kernel(
    const float* __restrict__ vws, const float* __restrict__ omws,
    const float* __restrict__ owt, const float* __restrict__ out_b,
    float* __restrict__ out)
{
  __shared__ float s_lds[128][68];   // stride 68: float4-aligned, spread banks
  __shared__ float owlds[64 * 64];   // owt staged; uniform reads -> broadcast
  const int t   = threadIdx.x;
  const int B   = blockIdx.x;        // 512 blocks
  const int xcd = B & 7;
  const int n   = xcd >> 1;
  const int row = ((xcd & 1) << 6) | (B >> 3);
  const int l0  = row << 7;

  {
    const float4* s4 = (const float4*)owt;    // 1024 float4
    float4*       d4 = (float4*)owlds;
    d4[t]       = s4[t];
    d4[512 + t] = s4[512 + t];
  }

  // ---- phase A: gather ----
  {
    const int p = t >> 2;            // 0..127 pixel-in-row
    const int g = t & 3;             // group
    const int l = l0 + p;
    const float pyf = (float)row;
    const float pxf = (float)p;
    const float* __restrict__ omp_  = omws + ((size_t)n * LL + l) * OMS + g * 28;
    const float* __restrict__ vbase = vws + (size_t)n * LL * CC + g * GCC;

    float buf[28];
    const float4* og4 = (const float4*)omp_;
    #pragma unroll
    for (int i = 0; i < 7; ++i) {
      const float4 vv = og4[i];
      buf[4*i+0] = vv.x; buf[4*i+1] = vv.y; buf[4*i+2] = vv.z; buf[4*i+3] = vv.w;
    }

    float s[16];
    #pragma unroll
    for (int i = 0; i < 16; ++i) s[i] = 0.0f;

    #pragma unroll
    for (int pp = 0; pp < 9; ++pp) {
      const float sy  = pyf + (float)(pp / 3 - 1) + buf[2*pp+1];
      const float sx  = pxf + (float)(pp % 3 - 1) + buf[2*pp+0];
      const float y0f = floorf(sy), x0f = floorf(sx);
      const float wy  = sy - y0f,  wx  = sx - x0f;
      const int   iy  = (int)y0f,  ix  = (int)x0f;
      const float m   = buf[18 + pp];
      const float w00 = (1.0f - wy) * (1.0f - wx) * m;
      const float w01 = (1.0f - wy) * wx * m;
      const float w10 = wy * (1.0f - wx) * m;
      const float w11 = wy * wx * m;
      #pragma unroll
      for (int cor = 0; cor < 4; ++cor) {
        const int   cy = iy + (cor >> 1);
        const int   cx = ix + (cor & 1);
        const float w  = (cor == 0) ? w00 : (cor == 1) ? w01 : (cor == 2) ? w10 : w11;
        if (cy >= 0 && cy < HH && cx >= 0 && cx < WW) {
          const float4* vp4 = (const float4*)(vbase + (size_t)(cy * WW + cx) * CC);
          #pragma unroll
          for (int qq = 0; qq < 4; ++qq) {
            const float4 vv = vp4[qq];
            s[4*qq+0] = fmaf(w, vv.x, s[4*qq+0]);
            s[4*qq+1] = fmaf(w, vv.y, s[4*qq+1]);
            s[4*qq+2] = fmaf(w, vv.z, s[4*qq+2]);
            s[4*qq+3] = fmaf(w, vv.w, s[4*qq+3]);
          }
        }
      }
    }
    #pragma unroll
    for (int q = 0; q < 4; ++q)
      *(float4*)&s_lds[p][g * 16 + q * 4] =
          make_float4(s[4*q+0], s[4*q+1], s[4*q+2], s[4*q+3]);
  }
  __syncthreads();

  // ---- phase B: output GEMV + NCHW store ----
  {
    const int w  = t >> 6;                 // wave id 0..7
    const int p  = (t & 63) | ((w & 1) << 6);   // pixel 0..127, lane-contiguous
    const int cq = w >> 1;                 // c-quarter, uniform per wave
    float y[16];
    #pragma unroll
    for (int j = 0; j < 16; ++j) y[j] = out_b[cq * 16 + j];
    #pragma unroll 4
    for (int k4 = 0; k4 < 16; ++k4) {
      const float4 sv = *(const float4*)&s_lds[p][k4 * 4];
      #pragma unroll
      for (int e = 0; e < 4; ++e) {
        const float se = (e == 0) ? sv.x : (e == 1) ? sv.y : (e == 2) ? sv.z : sv.w;
        const int   k  = k4 * 4 + e;
        #pragma unroll
        for (int q = 0; q < 4; ++q) {
          const float4 wv = *(const float4*)&owlds[k * 64 + cq * 16 + q * 4];
          y[q*4+0] = fmaf(se, wv.x, y[q*4+0]);
          y[q*4+1] = fmaf(se, wv.y, y[q*4+1]);
          y[q*4+2] = fmaf(se, wv.z, y[q*4+2]);
          y[q*4+3] = fmaf(se, wv.w, y[q*4+3]);
        }
      }
    }
    float* op = out + ((size_t)n * CC) * LL + l0 + p;
    #pragma unroll
    for (int j = 0; j < 16; ++j)
      op[(size_t)(cq * 16 + j) * LL] = y[j];   // 256B coalesced runs per wave
  }
}

// ---------------------------------------------------------------------------
extern "C" void kernel_launch(void* const* d_in, const int* in_sizes, int n_in,
                              void* d_out, int out_size, void* d_ws, size_t ws_size,
                              hipStream_t stream) {
  const float* x       = (const float*)d_in[0];
  const float* value_w = (const float*)d_in[1];
  const float* value_b = (const float*)d_in[2];
  const float* om_w    = (const float*)d_in[3];
  const float* om_b    = (const float*)d_in[4];
  const float* out_w   = (const float*)d_in[5];
  const float* out_b   = (const float*)d_in[6];
  float* outp = (float*)d_out;

  float* vws   = (float*)d_ws;                          // 4*16384*64  = 16 MB
  float* omws  = vws   + (size_t)NN * LL * CC;          // 4*16384*112 = 28 MB
  float* wpack = omws  + (size_t)NN * LL * OMS;         // 64*192 floats
  float* bpack = wpack + 64 * WPC;                      // 192 floats
  float* owt   = bpack + WPC;                           // 64*64 floats

  pack_kernel<<<dim3(48), dim3(256), 0, stream>>>(
      value_w, value_b, om_w, om_b, out_w, wpack, bpack, owt);
  vm_kernel<<<dim3(64, 11), dim3(256), 0, stream>>>(
      x, wpack, bpack, vws, omws);
  dcn_kernel<<<dim3(512), dim3(512), 0, stream>>>(
      vws, omws, owt, out_b, outp);
}

// Round 5
// 151.103 us; speedup vs baseline: 2.0654x; 1.0653x over previous
//
#include <hip/hip_runtime.h>

#define NN 4
#define CC 64
#define GG 4
#define GCC 16
#define HH 128
#define WW 128
#define LL (HH*WW)
#define OMS 112        /* om row stride (floats); group g at col 28g, 27 used + pad */
#define WPC 192        /* wpack row width: 64 v-cols | 112 om-cols (remapped) | 16 pad */

// ---------------------------------------------------------------------------
// Kernel 0: pack weights (wpack: transposed value_w|om_w with group-pad remap;
// bpack: matching bias columns; owt: out_w transposed).
// ---------------------------------------------------------------------------
__global__ void pack_kernel(const float* __restrict__ value_w, const float* __restrict__ value_b,
                            const float* __restrict__ om_w,    const float* __restrict__ om_b,
                            const float* __restrict__ out_w,
                            float* __restrict__ wpack, float* __restrict__ bpack,
                            float* __restrict__ owt)
{
  const int i = blockIdx.x * 256 + threadIdx.x;
  if (i < 64 * WPC) {
    const int k = i / WPC, c = i % WPC;
    float v = 0.0f;
    if (c < 64) v = value_w[c * 64 + k];
    else if (c < 176) {
      const int s = c - 64;
      if (s % 28 != 27) { const int r = s - s / 28; v = om_w[r * 64 + k]; }
    }
    wpack[i] = v;
  }
  if (i < WPC) {
    float v = 0.0f;
    if (i < 64) v = value_b[i];
    else if (i < 176) {
      const int s = i - 64;
      if (s % 28 != 27) { const int r = s - s / 28; v = om_b[r]; }
    }
    bpack[i] = v;
  }
  if (i < 64 * 64) {
    const int k = i >> 6, c = i & 63;
    owt[i] = out_w[c * 64 + k];
  }
}

// ---------------------------------------------------------------------------
// Kernel 1: x @ [value_w|om_w].T -> vws (64, pixel-major) + omws (112, padded)
//   (unchanged from round 4 — kept stable so its counters surface next round)
// ---------------------------------------------------------------------------
__global__ __launch_bounds__(256) void vm_kernel(
    const float* __restrict__ x, const float* __restrict__ wpack,
    const float* __restrict__ bpack,
    float* __restrict__ vws, float* __restrict__ omws)
{
  __shared__ float wlds[64][16];     // 4KB; uniform reads -> broadcast
  const int t    = threadIdx.x;
  const int ch   = blockIdx.y;       // 0..10
  const int col0 = ch << 4;

  {
    const int k = t >> 2, q = t & 3;
    *(float4*)&wlds[k][q * 4] =
        *(const float4*)&wpack[k * WPC + col0 + q * 4];
  }
  float b[16];
  #pragma unroll
  for (int j = 0; j < 16; ++j) b[j] = bpack[col0 + j];
  __syncthreads();

  const int l0 = blockIdx.x << 10;         // 1024 px per block (16 tiles / n)
  const int n  = l0 >> 14;
  const int hw = (l0 & (LL - 1)) + t;      // +0, +256, +512, +768

  float acc[4][16];
  #pragma unroll
  for (int pi = 0; pi < 4; ++pi)
    #pragma unroll
    for (int j = 0; j < 16; ++j) acc[pi][j] = b[j];

  const float* xb = x + (size_t)n * CC * LL + hw;
  #pragma unroll 8
  for (int k = 0; k < 64; ++k) {
    float xv[4];
    #pragma unroll
    for (int pi = 0; pi < 4; ++pi) xv[pi] = xb[(size_t)k * LL + pi * 256];
    #pragma unroll
    for (int q = 0; q < 4; ++q) {
      const float4 w = *(const float4*)&wlds[k][q * 4];
      #pragma unroll
      for (int pi = 0; pi < 4; ++pi) {
        acc[pi][q*4+0] = fmaf(xv[pi], w.x, acc[pi][q*4+0]);
        acc[pi][q*4+1] = fmaf(xv[pi], w.y, acc[pi][q*4+1]);
        acc[pi][q*4+2] = fmaf(xv[pi], w.z, acc[pi][q*4+2]);
        acc[pi][q*4+3] = fmaf(xv[pi], w.w, acc[pi][q*4+3]);
      }
    }
  }

  float* dst; int col; int stride;
  if (ch < 4) { dst = vws  + (size_t)n * LL * 64;  col = col0;      stride = 64;  }
  else        { dst = omws + (size_t)n * LL * OMS; col = col0 - 64; stride = OMS; }
  #pragma unroll
  for (int pi = 0; pi < 4; ++pi) {
    float* d = dst + (size_t)(hw + pi * 256) * stride + col;
    #pragma unroll
    for (int q = 0; q < 4; ++q)
      *(float4*)&d[q * 4] =
          make_float4(acc[pi][q*4+0], acc[pi][q*4+1], acc[pi][q*4+2], acc[pi][q*4+3]);
  }
}

// ---------------------------------------------------------------------------
// Kernel 2: deformable bilinear gather + output GEMV, NCHW store.
//   512 threads / block over 32 px (quarter-row). Grid 2048; XCD-aware:
//   n = (B&7)>>1 so each XCD's L2 holds exactly one image's v.
//   phase A: thread = (px, g, qq): ONE float4 per corner per lane; a wave's
//     4 qq lanes form a contiguous 64B segment -> ~4x fewer VMEM instructions
//     and ~8x fewer L1 line-touches than the (px,g)x4qq layout (L1-bound fix).
//   phase B: thread = (px, c4): 4 output channels, weights broadcast from LDS.
// ---------------------------------------------------------------------------
__global__ __launch_bounds__(512) void dcn_kernel(
    const float* __restrict__ vws, const float* __restrict__ omws,
    const float* __restrict__ owt, const float* __restrict__ out_b,
    float* __restrict__ out)
{
  __shared__ float s_lds[32][68];    // row stride 272B (16B-aligned)
  __shared__ float owlds[64 * 64];   // owt staged; uniform reads -> broadcast
  const int t   = threadIdx.x;
  const int B   = blockIdx.x;        // 2048 blocks
  const int xcd = B & 7;
  const int n   = xcd >> 1;
  const int idx = ((xcd & 1) << 8) | (B >> 3);   // 0..511 quarter-row slot
  const int row = idx >> 2;
  const int l0  = (row << 7) + ((idx & 3) << 5); // base pixel (32-px quarter)

  {
    const float4* s4 = (const float4*)owt;       // 1024 float4
    float4*       d4 = (float4*)owlds;
    d4[t]       = s4[t];
    d4[512 + t] = s4[512 + t];
  }

  // ---- phase A: gather ----
  {
    const int px = t >> 4;           // 0..31 pixel-in-quarter
    const int g  = (t >> 2) & 3;     // group
    const int qq = t & 3;            // channel-quad within group
    const int l  = l0 + px;
    const float pyf = (float)row;
    const float pxf = (float)(l & (WW - 1));
    const float* __restrict__ omp_  = omws + ((size_t)n * LL + l) * OMS + g * 28;
    const float* __restrict__ vbase = vws + (size_t)n * LL * CC + g * GCC + qq * 4;

    float buf[28];
    const float4* og4 = (const float4*)omp_;
    #pragma unroll
    for (int i = 0; i < 7; ++i) {
      const float4 vv = og4[i];
      buf[4*i+0] = vv.x; buf[4*i+1] = vv.y; buf[4*i+2] = vv.z; buf[4*i+3] = vv.w;
    }

    float s0 = 0.0f, s1 = 0.0f, s2 = 0.0f, s3 = 0.0f;

    #pragma unroll
    for (int pp = 0; pp < 9; ++pp) {
      const float sy  = pyf + (float)(pp / 3 - 1) + buf[2*pp+1];
      const float sx  = pxf + (float)(pp % 3 - 1) + buf[2*pp+0];
      const float y0f = floorf(sy), x0f = floorf(sx);
      const float wy  = sy - y0f,  wx  = sx - x0f;
      const int   iy  = (int)y0f,  ix  = (int)x0f;
      const float m   = buf[18 + pp];
      const float w00 = (1.0f - wy) * (1.0f - wx) * m;
      const float w01 = (1.0f - wy) * wx * m;
      const float w10 = wy * (1.0f - wx) * m;
      const float w11 = wy * wx * m;
      #pragma unroll
      for (int cor = 0; cor < 4; ++cor) {
        const int   cy = iy + (cor >> 1);
        const int   cx = ix + (cor & 1);
        const float w  = (cor == 0) ? w00 : (cor == 1) ? w01 : (cor == 2) ? w10 : w11;
        if (cy >= 0 && cy < HH && cx >= 0 && cx < WW) {
          const float4 vv = *(const float4*)(vbase + (size_t)(cy * WW + cx) * CC);
          s0 = fmaf(w, vv.x, s0);
          s1 = fmaf(w, vv.y, s1);
          s2 = fmaf(w, vv.z, s2);
          s3 = fmaf(w, vv.w, s3);
        }
      }
    }
    *(float4*)&s_lds[px][g * 16 + qq * 4] = make_float4(s0, s1, s2, s3);
  }
  __syncthreads();

  // ---- phase B: output GEMV + NCHW store ----
  {
    const int px = t & 31;           // pixel (lane-contiguous within half-wave)
    const int c4 = t >> 5;           // 0..15: output channel quad
    const int l  = l0 + px;
    float y0 = out_b[c4 * 4 + 0], y1 = out_b[c4 * 4 + 1];
    float y2 = out_b[c4 * 4 + 2], y3 = out_b[c4 * 4 + 3];
    #pragma unroll 4
    for (int k4 = 0; k4 < 16; ++k4) {
      const float4 sv = *(const float4*)&s_lds[px][k4 * 4];
      #pragma unroll
      for (int e = 0; e < 4; ++e) {
        const float se = (e == 0) ? sv.x : (e == 1) ? sv.y : (e == 2) ? sv.z : sv.w;
        const float4 wv = *(const float4*)&owlds[(k4 * 4 + e) * 64 + c4 * 4];
        y0 = fmaf(se, wv.x, y0);
        y1 = fmaf(se, wv.y, y1);
        y2 = fmaf(se, wv.z, y2);
        y3 = fmaf(se, wv.w, y3);
      }
    }
    float* op = out + ((size_t)n * CC) * LL + l;
    op[(size_t)(c4 * 4 + 0) * LL] = y0;      // 2x128B runs per wave-instr
    op[(size_t)(c4 * 4 + 1) * LL] = y1;
    op[(size_t)(c4 * 4 + 2) * LL] = y2;
    op[(size_t)(c4 * 4 + 3) * LL] = y3;
  }
}

// ---------------------------------------------------------------------------
extern "C" void kernel_launch(void* const* d_in, const int* in_sizes, int n_in,
                              void* d_out, int out_size, void* d_ws, size_t ws_size,
                              hipStream_t stream) {
  const float* x       = (const float*)d_in[0];
  const float* value_w = (const float*)d_in[1];
  const float* value_b = (const float*)d_in[2];
  const float* om_w    = (const float*)d_in[3];
  const float* om_b    = (const float*)d_in[4];
  const float* out_w   = (const float*)d_in[5];
  const float* out_b   = (const float*)d_in[6];
  float* outp = (float*)d_out;

  float* vws   = (float*)d_ws;                          // 4*16384*64  = 16 MB
  float* omws  = vws   + (size_t)NN * LL * CC;          // 4*16384*112 = 28 MB
  float* wpack = omws  + (size_t)NN * LL * OMS;         // 64*192 floats
  float* bpack = wpack + 64 * WPC;                      // 192 floats
  float* owt   = bpack + WPC;                           // 64*64 floats

  pack_kernel<<<dim3(48), dim3(256), 0, stream>>>(
      value_w, value_b, om_w, om_b, out_w, wpack, bpack, owt);
  vm_kernel<<<dim3(64, 11), dim3(256), 0, stream>>>(
      x, wpack, bpack, vws, omws);
  dcn_kernel<<<dim3(2048), dim3(512), 0, stream>>>(
      vws, omws, owt, out_b, outp);
}

// Round 6
// 137.727 us; speedup vs baseline: 2.2660x; 1.0971x over previous
//
#include <hip/hip_runtime.h>

#define NN 4
#define CC 64
#define GG 4
#define GCC 16
#define HH 128
#define WW 128
#define LL (HH*WW)
#define OMS 112        /* om row stride (floats); group g at col 28g, 27 used + pad */
#define WPC 192        /* packed col count: 64 v | 112 om (remapped) | 16 zero pad */

typedef __attribute__((ext_vector_type(8))) short bf16x8;   // 8 bf16 = 4 VGPR (guide-verified)
typedef __attribute__((ext_vector_type(4))) float f32x4;    // MFMA 16x16x32 C/D

// bf16x3 split: v = hi + lo with |err| ~ 2^-18 |v|
static __device__ __forceinline__ unsigned short f2bf(float x) {
  union { float f; unsigned u; } v; v.f = x;
  unsigned r = v.u + 0x7fff + ((v.u >> 16) & 1);   // RNE
  return (unsigned short)(r >> 16);
}
static __device__ __forceinline__ float bf2f(unsigned short s) {
  union { float f; unsigned u; } v; v.u = ((unsigned)s) << 16; return v.f;
}
static __device__ __forceinline__ void split2(float x, unsigned short& h, unsigned short& l) {
  h = f2bf(x);
  l = f2bf(x - bf2f(h));
}

// ---------------------------------------------------------------------------
// Kernel 0: pack + bf16-split weights.
//   wphi/wplo[c][k], c in 0..191 (value cols | remapped om cols | zero pad)
//   owhi/owlo[c][k] = split(out_w[c][k]);  bpack[c] = biases in packed order
// ---------------------------------------------------------------------------
__global__ void pack_kernel(const float* __restrict__ value_w, const float* __restrict__ value_b,
                            const float* __restrict__ om_w,    const float* __restrict__ om_b,
                            const float* __restrict__ out_w,
                            unsigned short* __restrict__ wphi, unsigned short* __restrict__ wplo,
                            unsigned short* __restrict__ owhi, unsigned short* __restrict__ owlo,
                            float* __restrict__ bpack)
{
  const int i = blockIdx.x * 256 + threadIdx.x;     // 48*256 = 12288 = WPC*64
  if (i < WPC * 64) {
    const int c = i >> 6, k = i & 63;
    float v = 0.0f;
    if (c < 64) v = value_w[c * 64 + k];
    else if (c < 176) {
      const int s = c - 64;
      if (s % 28 != 27) v = om_w[(s - s / 28) * 64 + k];
    }
    unsigned short h, l; split2(v, h, l);
    wphi[i] = h; wplo[i] = l;
  }
  if (i < 64 * 64) {                                 // out_w is [c][k] row-major already
    unsigned short h, l; split2(out_w[i], h, l);
    owhi[i] = h; owlo[i] = l;
  }
  if (i < WPC) {
    float v = 0.0f;
    if (i < 64) v = value_b[i];
    else if (i < 176) { const int s = i - 64; if (s % 28 != 27) v = om_b[s - s / 28]; }
    bpack[i] = v;
  }
}

// ---------------------------------------------------------------------------
// Kernel 1: bf16x3 MFMA GEMM  inp @ [value_w|om_w].T  -> vws + omws
//   grid (512 px-strips of 128, 3 col-groups); block 256 (4 waves).
//   Stage x strip -> LDS split bf16 [px][c] rows (A-frags, 144B rows, 16B-aligned).
//   Wave = 1 col-tile (16 cols): B-frags loaded once to VGPRs; loop 8 px-tiles:
//   6 mfma each (2 k-steps x {lo*hi, hi*lo, hi*hi}).
// ---------------------------------------------------------------------------
__global__ __launch_bounds__(256) void vm_kernel(
    const float* __restrict__ x,
    const unsigned short* __restrict__ wphi, const unsigned short* __restrict__ wplo,
    const float* __restrict__ bpack,
    float* __restrict__ vws, float* __restrict__ omws)
{
  __shared__ unsigned short ahi[128][72];   // 72-short rows: 144B = 9 quads (bank spread)
  __shared__ unsigned short alo[128][72];
  const int t   = threadIdx.x;
  const int sid = blockIdx.x;               // 0..511
  const int n   = sid >> 7;
  const int ll0 = (sid & 127) << 7;         // local pixel base within image
  const size_t gl0 = (size_t)sid << 7;      // global pixel base

  // stage + split x strip [64c][128px] -> ahi/alo[px][c]; 2 c per thread so the
  // hi/lo LDS writes are packed u32 (half the ds_write count)
  {
    const float* xb = x + (size_t)n * CC * LL + ll0;
    #pragma unroll
    for (int i = 0; i < 4; ++i) {
      const int pid = t + i * 256;          // 0..1023 = 32 c-pairs x 32 px-quads
      const int c   = (pid >> 5) << 1;
      const int px4 = (pid & 31) << 2;
      const float4 a = *(const float4*)(xb + (size_t)c * LL + px4);
      const float4 b = *(const float4*)(xb + (size_t)(c + 1) * LL + px4);
      const float av[4] = {a.x, a.y, a.z, a.w};
      const float bv[4] = {b.x, b.y, b.z, b.w};
      #pragma unroll
      for (int e = 0; e < 4; ++e) {
        unsigned short ha, la, hb, lb;
        split2(av[e], ha, la); split2(bv[e], hb, lb);
        *(unsigned*)&ahi[px4 + e][c] = (unsigned)ha | ((unsigned)hb << 16);
        *(unsigned*)&alo[px4 + e][c] = (unsigned)la | ((unsigned)lb << 16);
      }
    }
  }
  __syncthreads();

  const int w  = t >> 6;
  const int ln = t & 63;
  const int ct = blockIdx.y * 4 + w;        // col-tile 0..11 (11 = pad, not stored)
  const int c0 = ct << 4;
  const int r  = ln & 15;                   // A row / B col / D col
  const int kq = ln >> 4;                   // k-slice (operands) / row-group (D)

  bf16x8 Bh[2], Bl[2];
  #pragma unroll
  for (int ks = 0; ks < 2; ++ks) {
    Bh[ks] = *(const bf16x8*)&wphi[(c0 + r) * 64 + ks * 32 + kq * 8];
    Bl[ks] = *(const bf16x8*)&wplo[(c0 + r) * 64 + ks * 32 + kq * 8];
  }
  const float bias = bpack[c0 + r];

  #pragma unroll
  for (int pt = 0; pt < 8; ++pt) {
    bf16x8 Ah[2], Al[2];
    #pragma unroll
    for (int ks = 0; ks < 2; ++ks) {
      Ah[ks] = *(const bf16x8*)&ahi[pt * 16 + r][ks * 32 + kq * 8];
      Al[ks] = *(const bf16x8*)&alo[pt * 16 + r][ks * 32 + kq * 8];
    }
    f32x4 acc = {bias, bias, bias, bias};
    #pragma unroll
    for (int ks = 0; ks < 2; ++ks) {
      acc = __builtin_amdgcn_mfma_f32_16x16x32_bf16(Al[ks], Bh[ks], acc, 0, 0, 0);
      acc = __builtin_amdgcn_mfma_f32_16x16x32_bf16(Ah[ks], Bl[ks], acc, 0, 0, 0);
      acc = __builtin_amdgcn_mfma_f32_16x16x32_bf16(Ah[ks], Bh[ks], acc, 0, 0, 0);
    }
    // D: col = r, rows = kq*4 + j (consecutive pixels)
    if (ct < 4) {
      float* d = vws + (gl0 + pt * 16 + kq * 4) * 64 + c0 + r;
      d[0] = acc[0]; d[64] = acc[1]; d[128] = acc[2]; d[192] = acc[3];
    } else if (ct < 11) {
      float* d = omws + (gl0 + pt * 16 + kq * 4) * (size_t)OMS + (c0 - 64) + r;
      d[0] = acc[0]; d[OMS] = acc[1]; d[2 * OMS] = acc[2]; d[3 * OMS] = acc[3];
    }
  }
}

// ---------------------------------------------------------------------------
// Kernel 2: gather (unchanged math) + bf16x3 MFMA output GEMM + coalesced store
//   512 thr / 32 px; XCD-aware so each XCD's L2 holds one image's v.
//   phase A: (px,g,qq) one float4 per corner; s -> LDS as split bf16 A-rows
//   phase B: 8 waves = 2 px-tiles x 4 col-tiles, 6 mfma each; D -> y_lds
//   phase C: y_lds -> NCHW float4 stores (128B runs)
// ---------------------------------------------------------------------------
__global__ __launch_bounds__(512, 4) void dcn_kernel(
    const float* __restrict__ vws, const float* __restrict__ omws,
    const unsigned short* __restrict__ owhi, const unsigned short* __restrict__ owlo,
    const float* __restrict__ out_b,
    float* __restrict__ out)
{
  __shared__ unsigned short shi[32][72];
  __shared__ unsigned short slo[32][72];
  __shared__ float y_lds[32][68];
  const int t   = threadIdx.x;
  const int B   = blockIdx.x;               // 2048 blocks
  const int xcd = B & 7;
  const int n   = xcd >> 1;
  const int idx = ((xcd & 1) << 8) | (B >> 3);
  const int row = idx >> 2;
  const int l0  = (row << 7) + ((idx & 3) << 5);

  // ---- phase A: gather ----
  {
    const int px = t >> 4, g = (t >> 2) & 3, qq = t & 3;
    const int l  = l0 + px;
    const float pyf = (float)row;
    const float pxf = (float)(l & (WW - 1));
    const float* __restrict__ omp_  = omws + ((size_t)n * LL + l) * OMS + g * 28;
    const float* __restrict__ vbase = vws + (size_t)n * LL * CC + g * GCC + qq * 4;

    float buf[28];
    const float4* og4 = (const float4*)omp_;
    #pragma unroll
    for (int i = 0; i < 7; ++i) {
      const float4 vv = og4[i];
      buf[4*i+0] = vv.x; buf[4*i+1] = vv.y; buf[4*i+2] = vv.z; buf[4*i+3] = vv.w;
    }

    float s0 = 0.0f, s1 = 0.0f, s2 = 0.0f, s3 = 0.0f;
    #pragma unroll
    for (int pp = 0; pp < 9; ++pp) {
      const float sy  = pyf + (float)(pp / 3 - 1) + buf[2*pp+1];
      const float sx  = pxf + (float)(pp % 3 - 1) + buf[2*pp+0];
      const float y0f = floorf(sy), x0f = floorf(sx);
      const float wy  = sy - y0f,  wx  = sx - x0f;
      const int   iy  = (int)y0f,  ix  = (int)x0f;
      const float m   = buf[18 + pp];
      const float w00 = (1.0f - wy) * (1.0f - wx) * m;
      const float w01 = (1.0f - wy) * wx * m;
      const float w10 = wy * (1.0f - wx) * m;
      const float w11 = wy * wx * m;
      #pragma unroll
      for (int cor = 0; cor < 4; ++cor) {
        const int   cy = iy + (cor >> 1);
        const int   cx = ix + (cor & 1);
        const float wgt = (cor == 0) ? w00 : (cor == 1) ? w01 : (cor == 2) ? w10 : w11;
        if (cy >= 0 && cy < HH && cx >= 0 && cx < WW) {
          const float4 vv = *(const float4*)(vbase + (size_t)(cy * WW + cx) * CC);
          s0 = fmaf(wgt, vv.x, s0);
          s1 = fmaf(wgt, vv.y, s1);
          s2 = fmaf(wgt, vv.z, s2);
          s3 = fmaf(wgt, vv.w, s3);
        }
      }
    }
    unsigned short h0,u0,h1,u1,h2,u2,h3,u3;
    split2(s0,h0,u0); split2(s1,h1,u1); split2(s2,h2,u2); split2(s3,h3,u3);
    *(ushort4*)&shi[px][g * 16 + qq * 4] = make_ushort4(h0, h1, h2, h3);
    *(ushort4*)&slo[px][g * 16 + qq * 4] = make_ushort4(u0, u1, u2, u3);
  }
  __syncthreads();

  // ---- phase B: y = s @ out_w.T + out_b via bf16x3 MFMA ----
  {
    const int w  = t >> 6, ln = t & 63;
    const int pxt = w >> 2, ct = w & 3, c0 = ct << 4;
    const int r  = ln & 15, kq = ln >> 4;
    bf16x8 Ah[2], Al[2], Bh[2], Bl[2];
    #pragma unroll
    for (int ks = 0; ks < 2; ++ks) {
      Ah[ks] = *(const bf16x8*)&shi[pxt * 16 + r][ks * 32 + kq * 8];
      Al[ks] = *(const bf16x8*)&slo[pxt * 16 + r][ks * 32 + kq * 8];
      Bh[ks] = *(const bf16x8*)&owhi[(c0 + r) * 64 + ks * 32 + kq * 8];
      Bl[ks] = *(const bf16x8*)&owlo[(c0 + r) * 64 + ks * 32 + kq * 8];
    }
    const float bias = out_b[c0 + r];
    f32x4 acc = {bias, bias, bias, bias};
    #pragma unroll
    for (int ks = 0; ks < 2; ++ks) {
      acc = __builtin_amdgcn_mfma_f32_16x16x32_bf16(Al[ks], Bh[ks], acc, 0, 0, 0);
      acc = __builtin_amdgcn_mfma_f32_16x16x32_bf16(Ah[ks], Bl[ks], acc, 0, 0, 0);
      acc = __builtin_amdgcn_mfma_f32_16x16x32_bf16(Ah[ks], Bh[ks], acc, 0, 0, 0);
    }
    #pragma unroll
    for (int j = 0; j < 4; ++j)
      y_lds[pxt * 16 + kq * 4 + j][c0 + r] = acc[j];
  }
  __syncthreads();

  // ---- phase C: coalesced NCHW store ----
  {
    const int c = t >> 3, px4 = (t & 7) << 2;
    const float4 v = make_float4(y_lds[px4][c], y_lds[px4+1][c],
                                 y_lds[px4+2][c], y_lds[px4+3][c]);
    *(float4*)(out + ((size_t)n * CC + c) * LL + l0 + px4) = v;
  }
}

// ---------------------------------------------------------------------------
extern "C" void kernel_launch(void* const* d_in, const int* in_sizes, int n_in,
                              void* d_out, int out_size, void* d_ws, size_t ws_size,
                              hipStream_t stream) {
  const float* x       = (const float*)d_in[0];
  const float* value_w = (const float*)d_in[1];
  const float* value_b = (const float*)d_in[2];
  const float* om_w    = (const float*)d_in[3];
  const float* om_b    = (const float*)d_in[4];
  const float* out_w   = (const float*)d_in[5];
  const float* out_b   = (const float*)d_in[6];
  float* outp = (float*)d_out;

  float* vws   = (float*)d_ws;                        // 4*16384*64  f32 = 16.8 MB
  float* omws  = vws  + (size_t)NN * LL * CC;         // 4*16384*112 f32 = 29.4 MB
  float* bpack = omws + (size_t)NN * LL * OMS;        // 192 f32
  unsigned short* wphi = (unsigned short*)(bpack + WPC);
  unsigned short* wplo = wphi + WPC * 64;
  unsigned short* owhi = wplo + WPC * 64;
  unsigned short* owlo = owhi + 64 * 64;

  pack_kernel<<<dim3(48), dim3(256), 0, stream>>>(
      value_w, value_b, om_w, om_b, out_w, wphi, wplo, owhi, owlo, bpack);
  vm_kernel<<<dim3(512, 3), dim3(256), 0, stream>>>(
      x, wphi, wplo, bpack, vws, omws);
  dcn_kernel<<<dim3(2048), dim3(512), 0, stream>>>(
      vws, omws, owhi, owlo, out_b, outp);
}